// Round 3
// baseline (274.336 us; speedup 1.0000x reference)
//
#include <hip/hip_runtime.h>

#define IMG_H 512
#define IMG_W 512
#define RH 16            // output rows per block; 18 input rows read (1.125x halo)
#define NBX (IMG_H / RH) // 32 row-blocks

// Round-3 changes (theory: stall-bound — 3 waves/SIMD effective occupancy x
// 6 latency slots per row-step):
//  1. One unaligned (4B-aligned) float4 load per image per row covers cols
//     2t-1..2t+2 -> 2 vmem/row instead of 6, no halo cndmask/addressing.
//     Lanes 0/255 keep a float2+scalar path (branch is uniform in the two
//     interior waves; all addresses strictly in-bounds).
//  2. RH 32->16: 3072 blocks / 12288 waves (1.5x wave-slot supply) for
//     latency hiding; pipeline fully unrolled, compile-time indices.
//  Per-pixel math bit-identical to the verified round-0/2 versions.

typedef float v4f __attribute__((ext_vector_type(4), aligned(4)));
typedef float v2f __attribute__((ext_vector_type(2), aligned(8)));

__global__ __launch_bounds__(256) void ssim_main_kernel(
    const float* __restrict__ img1, const float* __restrict__ img2,
    double* __restrict__ partial)
{
    // f32-rounded Gaussian(sigma=1.5, k=3) weights, matching JAX's f32 computation
    constexpr float W_E = 0.30780133f;  // exp(-1/4.5)/(1+2exp(-1/4.5))
    constexpr float W_C = 0.38439734f;  // 1/(1+2exp(-1/4.5))
    constexpr float C1c = 1e-4f;
    constexpr float C2c = 9e-4f;

    const int t = threadIdx.x;
    const int y0 = blockIdx.x * RH;
    const size_t base = (size_t)blockIdx.y * (size_t)(IMG_H * IMG_W);
    const float* __restrict__ A = img1 + base;
    const float* __restrict__ B = img2 + base;
    const bool interior = (t != 0) & (t != 255);
    const int x = 2 * t;

    // rolling window of horizontal conv sums: [2 cols][3 row slots]
    float h1[2][3], h2[2][3], h11[2][3], h22[2][3], h12[2][3];
    float tsum = 0.0f;

    // two register row-buffers (names only; no runtime indexing)
    float a00, a01, a02, a03, b00, b01, b02, b03;  // buf0
    float a10, a11, a12, a13, b10, b11, b12, b13;  // buf1

    // cols 2t-1..2t+2 in one dwordx4 (4B-aligned is legal for dwordx4);
    // edge lanes diverge only inside waves 0 and 3.
#define LOADROW(AP, BP, OFF) do {                                       \
    if (interior) {                                                     \
        const v4f fa = *(const v4f*)(A + (OFF) - 1);                    \
        const v4f fb = *(const v4f*)(B + (OFF) - 1);                    \
        AP##0 = fa.x; AP##1 = fa.y; AP##2 = fa.z; AP##3 = fa.w;         \
        BP##0 = fb.x; BP##1 = fb.y; BP##2 = fb.z; BP##3 = fb.w;         \
    } else {                                                            \
        const v2f fa = *(const v2f*)(A + (OFF));                        \
        const v2f fb = *(const v2f*)(B + (OFF));                        \
        AP##1 = fa.x; AP##2 = fa.y; BP##1 = fb.x; BP##2 = fb.y;         \
        AP##0 = (t == 0) ? 0.0f : A[(OFF) - 1];                         \
        BP##0 = (t == 0) ? 0.0f : B[(OFF) - 1];                         \
        AP##3 = (t == 0) ? A[(OFF) + 2] : 0.0f;                         \
        BP##3 = (t == 0) ? B[(OFF) + 2] : 0.0f;                         \
    }                                                                   \
} while (0)

#define ZEROROW(AP, BP) do {                                            \
    AP##0 = 0.f; AP##1 = 0.f; AP##2 = 0.f; AP##3 = 0.f;                 \
    BP##0 = 0.f; BP##1 = 0.f; BP##2 = 0.f; BP##3 = 0.f;                 \
} while (0)

    // horizontal 3-tap pass for row in buffer (AP,BP) into window slot S
#define HPASS(AP, BP, S) do {                                               \
    const float sa0 = AP##0 * AP##0, sa1 = AP##1 * AP##1;                   \
    const float sa2 = AP##2 * AP##2, sa3 = AP##3 * AP##3;                   \
    const float sb0 = BP##0 * BP##0, sb1 = BP##1 * BP##1;                   \
    const float sb2 = BP##2 * BP##2, sb3 = BP##3 * BP##3;                   \
    const float p0 = AP##0 * BP##0, p1 = AP##1 * BP##1;                     \
    const float p2 = AP##2 * BP##2, p3 = AP##3 * BP##3;                     \
    h1[0][S]  = W_E * (AP##0 + AP##2) + W_C * AP##1;                        \
    h1[1][S]  = W_E * (AP##1 + AP##3) + W_C * AP##2;                        \
    h2[0][S]  = W_E * (BP##0 + BP##2) + W_C * BP##1;                        \
    h2[1][S]  = W_E * (BP##1 + BP##3) + W_C * BP##2;                        \
    h11[0][S] = W_E * (sa0 + sa2) + W_C * sa1;                              \
    h11[1][S] = W_E * (sa1 + sa3) + W_C * sa2;                              \
    h22[0][S] = W_E * (sb0 + sb2) + W_C * sb1;                              \
    h22[1][S] = W_E * (sb1 + sb3) + W_C * sb2;                              \
    h12[0][S] = W_E * (p0 + p2) + W_C * p1;                                 \
    h12[1][S] = W_E * (p1 + p3) + W_C * p2;                                 \
} while (0)

    // vertical 3-tap + SSIM; ends = slots E0,E1, middle = MID
#define VOUT(E0, E1, MID) do {                                              \
    _Pragma("unroll")                                                       \
    for (int c = 0; c < 2; ++c) {                                           \
        const float mu1 = W_E * (h1[c][E0] + h1[c][E1]) + W_C * h1[c][MID]; \
        const float mu2 = W_E * (h2[c][E0] + h2[c][E1]) + W_C * h2[c][MID]; \
        const float e11 = W_E * (h11[c][E0] + h11[c][E1]) + W_C * h11[c][MID]; \
        const float e22 = W_E * (h22[c][E0] + h22[c][E1]) + W_C * h22[c][MID]; \
        const float e12 = W_E * (h12[c][E0] + h12[c][E1]) + W_C * h12[c][MID]; \
        const float mu1s = mu1 * mu1, mu2s = mu2 * mu2, m12 = mu1 * mu2;    \
        const float s11 = e11 - mu1s, s22 = e22 - mu2s, s12 = e12 - m12;    \
        const float num = (2.0f * m12 + C1c) * (2.0f * s12 + C2c);          \
        const float den = (mu1s + mu2s + C1c) * (s11 + s22 + C2c);          \
        tsum += num / den;                                                  \
    }                                                                       \
} while (0)

    const size_t o = (size_t)y0 * IMG_W + x;  // elem offset of row y0, col x

    // prologue: input row y0-1 -> buf0 (zeros above the image; uniform branch)
    if (blockIdx.x != 0) LOADROW(a0, b0, o - IMG_W); else ZEROROW(a0, b0);
    // step 0: prefetch row y0 -> buf1; consume buf0 into slot 0
    LOADROW(a1, b1, o);
    HPASS(a0, b0, 0);
    // step 1: prefetch row y0+1 -> buf0; consume buf1 into slot 1
    LOADROW(a0, b0, o + IMG_W);
    HPASS(a1, b1, 1);
    // steps 2..15: prefetch row y0+i (all interior); consume buf(i%2) into
    // slot (i%3); emit output row y0+i-2. Fully unrolled, compile-time idx.
    LOADROW(a1, b1, o +  2*IMG_W); HPASS(a0, b0, 2); VOUT(2, 0, 1);
    LOADROW(a0, b0, o +  3*IMG_W); HPASS(a1, b1, 0); VOUT(0, 1, 2);
    LOADROW(a1, b1, o +  4*IMG_W); HPASS(a0, b0, 1); VOUT(1, 2, 0);
    LOADROW(a0, b0, o +  5*IMG_W); HPASS(a1, b1, 2); VOUT(2, 0, 1);
    LOADROW(a1, b1, o +  6*IMG_W); HPASS(a0, b0, 0); VOUT(0, 1, 2);
    LOADROW(a0, b0, o +  7*IMG_W); HPASS(a1, b1, 1); VOUT(1, 2, 0);
    LOADROW(a1, b1, o +  8*IMG_W); HPASS(a0, b0, 2); VOUT(2, 0, 1);
    LOADROW(a0, b0, o +  9*IMG_W); HPASS(a1, b1, 0); VOUT(0, 1, 2);
    LOADROW(a1, b1, o + 10*IMG_W); HPASS(a0, b0, 1); VOUT(1, 2, 0);
    LOADROW(a0, b0, o + 11*IMG_W); HPASS(a1, b1, 2); VOUT(2, 0, 1);
    LOADROW(a1, b1, o + 12*IMG_W); HPASS(a0, b0, 0); VOUT(0, 1, 2);
    LOADROW(a0, b0, o + 13*IMG_W); HPASS(a1, b1, 1); VOUT(1, 2, 0);
    LOADROW(a1, b1, o + 14*IMG_W); HPASS(a0, b0, 2); VOUT(2, 0, 1);
    LOADROW(a0, b0, o + 15*IMG_W); HPASS(a1, b1, 0); VOUT(0, 1, 2);
    // step 16: prefetch row y0+16 (zeros below image for last block);
    // consume buf0 into slot 1
    if (blockIdx.x != NBX - 1) LOADROW(a1, b1, o + 16*IMG_W);
    else                       ZEROROW(a1, b1);
    HPASS(a0, b0, 1); VOUT(1, 2, 0);
    // step 17: consume buf1 into slot 2
    HPASS(a1, b1, 2); VOUT(2, 0, 1);

#undef LOADROW
#undef ZEROROW
#undef HPASS
#undef VOUT

    // 64-lane wave reduction (f32, same order as before)
#pragma unroll
    for (int off = 32; off >= 1; off >>= 1)
        tsum += __shfl_xor(tsum, off, 64);

    __shared__ float wpart[4];
    if ((t & 63) == 0) wpart[t >> 6] = tsum;
    __syncthreads();
    if (t == 0) {
        partial[(size_t)blockIdx.y * gridDim.x + blockIdx.x] =
            (double)wpart[0] + (double)wpart[1] +
            (double)wpart[2] + (double)wpart[3];
    }
}

// Reduce 3072 per-block double partials -> out = 1 - sum. One block.
__global__ __launch_bounds__(256) void ssim_fin_kernel(
    const double* __restrict__ partial, float* __restrict__ out, int n)
{
    const int t = threadIdx.x;
    double s = 0.0;
    for (int i = t; i < n; i += 256) s += partial[i];
#pragma unroll
    for (int o = 32; o >= 1; o >>= 1)
        s += __shfl_xor(s, o, 64);
    __shared__ double w[4];
    if ((t & 63) == 0) w[t >> 6] = s;
    __syncthreads();
    if (t == 0)
        out[0] = 1.0f - (float)(w[0] + w[1] + w[2] + w[3]);
}

extern "C" void kernel_launch(void* const* d_in, const int* in_sizes, int n_in,
                              void* d_out, int out_size, void* d_ws, size_t ws_size,
                              hipStream_t stream) {
    const float* img1 = (const float*)d_in[0];
    const float* img2 = (const float*)d_in[1];
    float* out = (float*)d_out;
    double* partial = (double*)d_ws;  // needs 32*96*8 = 24576 B of workspace

    const int planes = in_sizes[0] / (IMG_H * IMG_W);  // 32*3 = 96

    dim3 grid(NBX, planes);
    ssim_main_kernel<<<grid, 256, 0, stream>>>(img1, img2, partial);
    ssim_fin_kernel<<<1, 256, 0, stream>>>(partial, out, NBX * planes);
}

// Round 4
// 255.761 us; speedup vs baseline: 1.0726x; 1.0726x over previous
//
#include <hip/hip_runtime.h>

#define IMG_H 512
#define IMG_W 512
#define RH 32   // output rows per block; 34 input rows read (1.0625x halo overfetch)

// Round-4: EXACTLY round 2 (89.4 us: rotation loop, RH=32, no LDS, no
// barriers, VGPR 48, all 1536 blocks device-resident) with ONE change:
// interior lanes load cols 2t-1..2t+2 as a single 4B-aligned float4 per
// image (2 vmem/row instead of 6) -> fewer latency slots + less halo
// addressing VALU, same bytes. Edge lanes t=0/255 keep the scalar path
// (diverges only at lane 0 of wave 0 / lane 63 of wave 3).
// Round-3 lesson encoded here: do NOT fully unroll the row pipeline —
// it inflates VGPR to 112, halves resident waves, and costs +50% time.
// Per-pixel math bit-identical to the verified round-0/2 versions.

typedef float v4f __attribute__((ext_vector_type(4), aligned(4)));
typedef float v2f __attribute__((ext_vector_type(2), aligned(8)));

__global__ __launch_bounds__(256) void ssim_main_kernel(
    const float* __restrict__ img1, const float* __restrict__ img2,
    double* __restrict__ partial)
{
    // f32-rounded Gaussian(sigma=1.5, k=3) weights, matching JAX's f32 computation
    constexpr float W_E = 0.30780133f;  // exp(-1/4.5)/(1+2exp(-1/4.5))
    constexpr float W_C = 0.38439734f;  // 1/(1+2exp(-1/4.5))
    constexpr float C1c = 1e-4f;
    constexpr float C2c = 9e-4f;

    const int t = threadIdx.x;
    const int y0 = blockIdx.x * RH;
    const size_t base = (size_t)blockIdx.y * (size_t)(IMG_H * IMG_W);
    const float* __restrict__ A = img1 + base;
    const float* __restrict__ B = img2 + base;
    const bool interior = (t != 0) & (t != 255);
    const int x = 2 * t;

    // rolling window of horizontal conv sums: [2 cols][3 row slots]
    float h1[2][3], h2[2][3], h11[2][3], h22[2][3], h12[2][3];
    float tsum = 0.0f;

    // two register row-buffers (names only; no runtime indexing)
    float a00, a01, a02, a03, b00, b01, b02, b03;  // buf0
    float a10, a11, a12, a13, b10, b11, b12, b13;  // buf1

    // cols 2t-1..2t+2 in one dwordx4 (4B alignment is legal for dwordx4);
    // edge lanes diverge only inside waves 0 and 3.
#define LOADROW(AP, BP, OFF) do {                                       \
    if (interior) {                                                     \
        const v4f fa = *(const v4f*)(A + (OFF) - 1);                    \
        const v4f fb = *(const v4f*)(B + (OFF) - 1);                    \
        AP##0 = fa.x; AP##1 = fa.y; AP##2 = fa.z; AP##3 = fa.w;         \
        BP##0 = fb.x; BP##1 = fb.y; BP##2 = fb.z; BP##3 = fb.w;         \
    } else {                                                            \
        const v2f fa = *(const v2f*)(A + (OFF));                        \
        const v2f fb = *(const v2f*)(B + (OFF));                        \
        AP##1 = fa.x; AP##2 = fa.y; BP##1 = fb.x; BP##2 = fb.y;         \
        AP##0 = (t == 0) ? 0.0f : A[(OFF) - 1];                         \
        BP##0 = (t == 0) ? 0.0f : B[(OFF) - 1];                         \
        AP##3 = (t == 0) ? A[(OFF) + 2] : 0.0f;                         \
        BP##3 = (t == 0) ? B[(OFF) + 2] : 0.0f;                         \
    }                                                                   \
} while (0)

#define ZEROROW(AP, BP) do {                                            \
    AP##0 = 0.f; AP##1 = 0.f; AP##2 = 0.f; AP##3 = 0.f;                 \
    BP##0 = 0.f; BP##1 = 0.f; BP##2 = 0.f; BP##3 = 0.f;                 \
} while (0)

    // horizontal 3-tap pass for row in buffer (AP,BP) into window slot S
#define HPASS(AP, BP, S) do {                                               \
    const float sa0 = AP##0 * AP##0, sa1 = AP##1 * AP##1;                   \
    const float sa2 = AP##2 * AP##2, sa3 = AP##3 * AP##3;                   \
    const float sb0 = BP##0 * BP##0, sb1 = BP##1 * BP##1;                   \
    const float sb2 = BP##2 * BP##2, sb3 = BP##3 * BP##3;                   \
    const float p0 = AP##0 * BP##0, p1 = AP##1 * BP##1;                     \
    const float p2 = AP##2 * BP##2, p3 = AP##3 * BP##3;                     \
    h1[0][S]  = W_E * (AP##0 + AP##2) + W_C * AP##1;                        \
    h1[1][S]  = W_E * (AP##1 + AP##3) + W_C * AP##2;                        \
    h2[0][S]  = W_E * (BP##0 + BP##2) + W_C * BP##1;                        \
    h2[1][S]  = W_E * (BP##1 + BP##3) + W_C * BP##2;                        \
    h11[0][S] = W_E * (sa0 + sa2) + W_C * sa1;                              \
    h11[1][S] = W_E * (sa1 + sa3) + W_C * sa2;                              \
    h22[0][S] = W_E * (sb0 + sb2) + W_C * sb1;                              \
    h22[1][S] = W_E * (sb1 + sb3) + W_C * sb2;                              \
    h12[0][S] = W_E * (p0 + p2) + W_C * p1;                                 \
    h12[1][S] = W_E * (p1 + p3) + W_C * p2;                                 \
} while (0)

    // vertical 3-tap + SSIM; ends = slots E0,E1, middle = MID
#define VOUT(E0, E1, MID) do {                                              \
    _Pragma("unroll")                                                       \
    for (int c = 0; c < 2; ++c) {                                           \
        const float mu1 = W_E * (h1[c][E0] + h1[c][E1]) + W_C * h1[c][MID]; \
        const float mu2 = W_E * (h2[c][E0] + h2[c][E1]) + W_C * h2[c][MID]; \
        const float e11 = W_E * (h11[c][E0] + h11[c][E1]) + W_C * h11[c][MID]; \
        const float e22 = W_E * (h22[c][E0] + h22[c][E1]) + W_C * h22[c][MID]; \
        const float e12 = W_E * (h12[c][E0] + h12[c][E1]) + W_C * h12[c][MID]; \
        const float mu1s = mu1 * mu1, mu2s = mu2 * mu2, m12 = mu1 * mu2;    \
        const float s11 = e11 - mu1s, s22 = e22 - mu2s, s12 = e12 - m12;    \
        const float num = (2.0f * m12 + C1c) * (2.0f * s12 + C2c);          \
        const float den = (mu1s + mu2s + C1c) * (s11 + s22 + C2c);          \
        tsum += num / den;                                                  \
    }                                                                       \
} while (0)

    size_t off = (size_t)y0 * IMG_W + x;  // element offset of row y0, col x

    // i=0: input row y0-1 -> buf0 (zeros above the image; uniform branch)
    if (blockIdx.x != 0) LOADROW(a0, b0, off - IMG_W); else ZEROROW(a0, b0);
    // prefetch i=1: row y0 -> buf1
    LOADROW(a1, b1, off);
    HPASS(a0, b0, 0);
    // i=1: prefetch row y0+1 -> buf0; consume buf1 into slot 1
    LOADROW(a0, b0, off + IMG_W);
    HPASS(a1, b1, 1);
    off += 2 * (size_t)IMG_W;  // next row to load: y0+2

    // middle steps i=2..31 (rows y0+1..y0+30 consumed; rows y0+2..y0+31
    // prefetched — all interior). 30 steps = 5 groups of 6 (period lcm(3,2));
    // pattern per step i: consume buf(i%2) slot (i%3).
#pragma unroll 1
    for (int g = 0; g < 5; ++g) {
        LOADROW(a1, b1, off); off += IMG_W; HPASS(a0, b0, 2); VOUT(2, 0, 1);
        LOADROW(a0, b0, off); off += IMG_W; HPASS(a1, b1, 0); VOUT(0, 1, 2);
        LOADROW(a1, b1, off); off += IMG_W; HPASS(a0, b0, 1); VOUT(1, 2, 0);
        LOADROW(a0, b0, off); off += IMG_W; HPASS(a1, b1, 2); VOUT(2, 0, 1);
        LOADROW(a1, b1, off); off += IMG_W; HPASS(a0, b0, 0); VOUT(0, 1, 2);
        LOADROW(a0, b0, off); off += IMG_W; HPASS(a1, b1, 1); VOUT(1, 2, 0);
    }

    // i=32: consume buf0 slot 2; prefetch last input row y0+32 (zeros below image)
    if (blockIdx.x != (IMG_H / RH - 1)) LOADROW(a1, b1, off); else ZEROROW(a1, b1);
    HPASS(a0, b0, 2); VOUT(2, 0, 1);
    // i=33: consume buf1 slot 0
    HPASS(a1, b1, 0); VOUT(0, 1, 2);

#undef LOADROW
#undef ZEROROW
#undef HPASS
#undef VOUT

    // 64-lane wave reduction (f32, same order as before)
#pragma unroll
    for (int o = 32; o >= 1; o >>= 1)
        tsum += __shfl_xor(tsum, o, 64);

    __shared__ float wpart[4];
    if ((t & 63) == 0) wpart[t >> 6] = tsum;
    __syncthreads();
    if (t == 0) {
        partial[(size_t)blockIdx.y * gridDim.x + blockIdx.x] =
            (double)wpart[0] + (double)wpart[1] +
            (double)wpart[2] + (double)wpart[3];
    }
}

// Reduce 1536 per-block double partials -> out = 1 - sum. One block.
__global__ __launch_bounds__(256) void ssim_fin_kernel(
    const double* __restrict__ partial, float* __restrict__ out, int n)
{
    const int t = threadIdx.x;
    double s = 0.0;
    for (int i = t; i < n; i += 256) s += partial[i];
#pragma unroll
    for (int o = 32; o >= 1; o >>= 1)
        s += __shfl_xor(s, o, 64);
    __shared__ double w[4];
    if ((t & 63) == 0) w[t >> 6] = s;
    __syncthreads();
    if (t == 0)
        out[0] = 1.0f - (float)(w[0] + w[1] + w[2] + w[3]);
}

extern "C" void kernel_launch(void* const* d_in, const int* in_sizes, int n_in,
                              void* d_out, int out_size, void* d_ws, size_t ws_size,
                              hipStream_t stream) {
    const float* img1 = (const float*)d_in[0];
    const float* img2 = (const float*)d_in[1];
    float* out = (float*)d_out;
    double* partial = (double*)d_ws;  // needs 16*96*8 = 12288 B of workspace

    const int planes = in_sizes[0] / (IMG_H * IMG_W);  // 32*3 = 96
    const int nblk = IMG_H / RH;                        // 16

    dim3 grid(nblk, planes);
    ssim_main_kernel<<<grid, 256, 0, stream>>>(img1, img2, partial);
    ssim_fin_kernel<<<1, 256, 0, stream>>>(partial, out, nblk * planes);
}

// Round 5
// 228.361 us; speedup vs baseline: 1.2013x; 1.1200x over previous
//
#include <hip/hip_runtime.h>

#define IMG_H 512
#define IMG_W 512
#define RH 32   // output rows per block; 34 input rows read (1.0625x halo overfetch)

// Round-5: EXACTLY round 2 (89.4 us: rotation loop, RH=32, no LDS/barriers,
// float2+predicated-scalar halo loads, VGPR 48) with ONE change: prefetch
// depth 1 -> 2 (THREE register row-buffers, period lcm(3,3)=3). Load-to-use
// distance = 3 row-steps (~750 issue-cycles) to cover HBM-miss latency
// (~900cy; FETCH_SIZE shows ~half the reads miss L3). Theory: all prior
// variants share 1-row slack and all land >= 89 us regardless of structure
// -> latency-exposure-bound, not instruction-bound.
// Round-3/4 lessons encoded: no full unroll (VGPR bloat), no misaligned
// dwordx4 (2x L1 transactions per load).
// Per-pixel math and accumulation order bit-identical to round 0/2 (absmax 0).

typedef float v2f __attribute__((ext_vector_type(2), aligned(8)));

__global__ __launch_bounds__(256) void ssim_main_kernel(
    const float* __restrict__ img1, const float* __restrict__ img2,
    double* __restrict__ partial)
{
    // f32-rounded Gaussian(sigma=1.5, k=3) weights, matching JAX's f32 computation
    constexpr float W_E = 0.30780133f;  // exp(-1/4.5)/(1+2exp(-1/4.5))
    constexpr float W_C = 0.38439734f;  // 1/(1+2exp(-1/4.5))
    constexpr float C1c = 1e-4f;
    constexpr float C2c = 9e-4f;

    const int t = threadIdx.x;
    const int y0 = blockIdx.x * RH;
    const size_t base = (size_t)blockIdx.y * (size_t)(IMG_H * IMG_W);
    const float* __restrict__ A = img1 + base;
    const float* __restrict__ B = img2 + base;
    const bool has_l = (t > 0);    // col 2t-1 exists (else zero border)
    const bool has_r = (t < 255);  // col 2t+2 exists (else zero border)
    const int x = 2 * t;

    // rolling window of horizontal conv sums: [2 cols][3 row slots]
    float h1[2][3], h2[2][3], h11[2][3], h22[2][3], h12[2][3];
    float tsum = 0.0f;

    // THREE register row-buffers (names only; no runtime indexing)
    float a00, a01, a02, a03, b00, b01, b02, b03;  // buf0
    float a10, a11, a12, a13, b10, b11, b12, b13;  // buf1
    float a20, a21, a22, a23, b20, b21, b22, b23;  // buf2

#define LOADROW(AP, BP, OFF) do {                                   \
    const v2f _ma = *(const v2f*)(A + (OFF));                       \
    const v2f _mb = *(const v2f*)(B + (OFF));                       \
    AP##1 = _ma.x; AP##2 = _ma.y; BP##1 = _mb.x; BP##2 = _mb.y;     \
    AP##0 = has_l ? A[(OFF) - 1] : 0.0f;                            \
    AP##3 = has_r ? A[(OFF) + 2] : 0.0f;                            \
    BP##0 = has_l ? B[(OFF) - 1] : 0.0f;                            \
    BP##3 = has_r ? B[(OFF) + 2] : 0.0f;                            \
} while (0)

#define ZEROROW(AP, BP) do {                                        \
    AP##0 = 0.f; AP##1 = 0.f; AP##2 = 0.f; AP##3 = 0.f;             \
    BP##0 = 0.f; BP##1 = 0.f; BP##2 = 0.f; BP##3 = 0.f;             \
} while (0)

    // horizontal 3-tap pass for row in buffer (AP,BP) into window slot S
#define HPASS(AP, BP, S) do {                                               \
    const float sa0 = AP##0 * AP##0, sa1 = AP##1 * AP##1;                   \
    const float sa2 = AP##2 * AP##2, sa3 = AP##3 * AP##3;                   \
    const float sb0 = BP##0 * BP##0, sb1 = BP##1 * BP##1;                   \
    const float sb2 = BP##2 * BP##2, sb3 = BP##3 * BP##3;                   \
    const float p0 = AP##0 * BP##0, p1 = AP##1 * BP##1;                     \
    const float p2 = AP##2 * BP##2, p3 = AP##3 * BP##3;                     \
    h1[0][S]  = W_E * (AP##0 + AP##2) + W_C * AP##1;                        \
    h1[1][S]  = W_E * (AP##1 + AP##3) + W_C * AP##2;                        \
    h2[0][S]  = W_E * (BP##0 + BP##2) + W_C * BP##1;                        \
    h2[1][S]  = W_E * (BP##1 + BP##3) + W_C * BP##2;                        \
    h11[0][S] = W_E * (sa0 + sa2) + W_C * sa1;                              \
    h11[1][S] = W_E * (sa1 + sa3) + W_C * sa2;                              \
    h22[0][S] = W_E * (sb0 + sb2) + W_C * sb1;                              \
    h22[1][S] = W_E * (sb1 + sb3) + W_C * sb2;                              \
    h12[0][S] = W_E * (p0 + p2) + W_C * p1;                                 \
    h12[1][S] = W_E * (p1 + p3) + W_C * p2;                                 \
} while (0)

    // vertical 3-tap + SSIM; ends = slots E0,E1, middle = MID
#define VOUT(E0, E1, MID) do {                                              \
    _Pragma("unroll")                                                       \
    for (int c = 0; c < 2; ++c) {                                           \
        const float mu1 = W_E * (h1[c][E0] + h1[c][E1]) + W_C * h1[c][MID]; \
        const float mu2 = W_E * (h2[c][E0] + h2[c][E1]) + W_C * h2[c][MID]; \
        const float e11 = W_E * (h11[c][E0] + h11[c][E1]) + W_C * h11[c][MID]; \
        const float e22 = W_E * (h22[c][E0] + h22[c][E1]) + W_C * h22[c][MID]; \
        const float e12 = W_E * (h12[c][E0] + h12[c][E1]) + W_C * h12[c][MID]; \
        const float mu1s = mu1 * mu1, mu2s = mu2 * mu2, m12 = mu1 * mu2;    \
        const float s11 = e11 - mu1s, s22 = e22 - mu2s, s12 = e12 - m12;    \
        const float num = (2.0f * m12 + C1c) * (2.0f * s12 + C2c);          \
        const float den = (mu1s + mu2s + C1c) * (s11 + s22 + C2c);          \
        tsum += num / den;                                                  \
    }                                                                       \
} while (0)

    size_t off = (size_t)y0 * IMG_W + x;  // element offset of row y0, col x

    // prologue: rows y0-1 -> buf0 (zeros above image), y0 -> buf1, y0+1 -> buf2
    if (blockIdx.x != 0) LOADROW(a0, b0, off - IMG_W); else ZEROROW(a0, b0);
    LOADROW(a1, b1, off);             // y0      (always in-bounds)
    LOADROW(a2, b2, off + IMG_W);     // y0+1    (<= 481, in-bounds)

    // step i consumes input row y0-1+i from buf(i%3) into slot (i%3), then
    // reloads that buffer with row y0+2+i (consumed at step i+3).
    // step 0: consume buf0 (row y0-1); reload buf0 <- y0+2
    HPASS(a0, b0, 0);
    LOADROW(a0, b0, off + 2 * IMG_W); // y0+2 (<= 482, in-bounds)
    // step 1: consume buf1 (row y0); reload buf1 <- y0+3
    HPASS(a1, b1, 1);
    LOADROW(a1, b1, off + 3 * IMG_W); // y0+3 (<= 483, in-bounds)

    off += 4 * (size_t)IMG_W;         // next load row: y0+4
    int rload = y0 + 4;

    // steps 2..31: 10 groups of 3 (buffers and slots coincide, period 3).
    // Loads cover rows y0+4 .. y0+33; guard (uniform per block) zero-fills
    // rows below the image. Output rows y0 .. y0+29 emitted here.
#pragma unroll 1
    for (int g = 0; g < 10; ++g) {
        HPASS(a2, b2, 2); VOUT(2, 0, 1);
        if (rload < IMG_H) LOADROW(a2, b2, off); else ZEROROW(a2, b2);
        off += IMG_W; ++rload;
        HPASS(a0, b0, 0); VOUT(0, 1, 2);
        if (rload < IMG_H) LOADROW(a0, b0, off); else ZEROROW(a0, b0);
        off += IMG_W; ++rload;
        HPASS(a1, b1, 1); VOUT(1, 2, 0);
        if (rload < IMG_H) LOADROW(a1, b1, off); else ZEROROW(a1, b1);
        off += IMG_W; ++rload;
    }

    // step 32: consume buf2 = row y0+31 -> output row y0+30
    HPASS(a2, b2, 2); VOUT(2, 0, 1);
    // step 33: consume buf0 = row y0+32 (zeros below image for last block)
    //          -> output row y0+31.  (buf1 holds y0+33, unused.)
    HPASS(a0, b0, 0); VOUT(0, 1, 2);

#undef LOADROW
#undef ZEROROW
#undef HPASS
#undef VOUT

    // 64-lane wave reduction (f32, same order as before)
#pragma unroll
    for (int o = 32; o >= 1; o >>= 1)
        tsum += __shfl_xor(tsum, o, 64);

    __shared__ float wpart[4];
    if ((t & 63) == 0) wpart[t >> 6] = tsum;
    __syncthreads();
    if (t == 0) {
        partial[(size_t)blockIdx.y * gridDim.x + blockIdx.x] =
            (double)wpart[0] + (double)wpart[1] +
            (double)wpart[2] + (double)wpart[3];
    }
}

// Reduce 1536 per-block double partials -> out = 1 - sum. One block.
__global__ __launch_bounds__(256) void ssim_fin_kernel(
    const double* __restrict__ partial, float* __restrict__ out, int n)
{
    const int t = threadIdx.x;
    double s = 0.0;
    for (int i = t; i < n; i += 256) s += partial[i];
#pragma unroll
    for (int o = 32; o >= 1; o >>= 1)
        s += __shfl_xor(s, o, 64);
    __shared__ double w[4];
    if ((t & 63) == 0) w[t >> 6] = s;
    __syncthreads();
    if (t == 0)
        out[0] = 1.0f - (float)(w[0] + w[1] + w[2] + w[3]);
}

extern "C" void kernel_launch(void* const* d_in, const int* in_sizes, int n_in,
                              void* d_out, int out_size, void* d_ws, size_t ws_size,
                              hipStream_t stream) {
    const float* img1 = (const float*)d_in[0];
    const float* img2 = (const float*)d_in[1];
    float* out = (float*)d_out;
    double* partial = (double*)d_ws;  // needs 16*96*8 = 12288 B of workspace

    const int planes = in_sizes[0] / (IMG_H * IMG_W);  // 32*3 = 96
    const int nblk = IMG_H / RH;                        // 16

    dim3 grid(nblk, planes);
    ssim_main_kernel<<<grid, 256, 0, stream>>>(img1, img2, partial);
    ssim_fin_kernel<<<1, 256, 0, stream>>>(partial, out, nblk * planes);
}

// Round 6
// 225.805 us; speedup vs baseline: 1.2149x; 1.0113x over previous
//
#include <hip/hip_runtime.h>

#define IMG_H 512
#define IMG_W 512
#define RH 32            // output rows per block; 34 input rows consumed
#define NBX (IMG_H / RH) // 16 row-blocks

// Round-6: LDS double-buffered 3-ROW SUPERSTEPS (12 barriers vs r0's 34).
// Body order per superstep s: WRITE3(stage s+1 regs -> LDS) ; LOAD3(stage
// s+2 -> regs, ~800cy in flight during compute) ; compute 3 row-steps from
// buf(s&1) ; __syncthreads. The barrier's implicit vmcnt(0) drain is nearly
// free because the loads were issued a full compute-phase earlier.
// LDS zero-borders restore free halos (no cndmask / predicated scalar
// loads); 2 global loads per row per thread, all work from LDS.
// 3 rows/superstep == 0 mod 3 window slots -> identical slot pattern every
// superstep (loop stays rolled; no r3-style VGPR bloat).
// LDS 24,960 B/block -> 6 blocks/CU -> entire 1536-block grid resident.
// Per-pixel math and accumulation order bit-identical to r0/r2/r5 (absmax 0).

typedef float v2f __attribute__((ext_vector_type(2), aligned(8)));

__global__ __launch_bounds__(256) void ssim_main_kernel(
    const float* __restrict__ img1, const float* __restrict__ img2,
    double* __restrict__ partial)
{
    // f32-rounded Gaussian(sigma=1.5, k=3) weights, matching JAX's f32 computation
    constexpr float W_E = 0.30780133f;  // exp(-1/4.5)/(1+2exp(-1/4.5))
    constexpr float W_C = 0.38439734f;  // 1/(1+2exp(-1/4.5))
    constexpr float C1c = 1e-4f;
    constexpr float C2c = 9e-4f;

    const int t = threadIdx.x;
    const int y0 = blockIdx.x * RH;
    const size_t base = (size_t)blockIdx.y * (size_t)(IMG_H * IMG_W);
    const float* __restrict__ A = img1 + base;
    const float* __restrict__ B = img2 + base;
    const int x = 2 * t;

    // [buf][row][col+1]; cols 0 and 513 are permanent zero borders
    __shared__ float lsA[2][3][520];
    __shared__ float lsB[2][3][520];
    if (t < 24) {                      // 2 arrays x 2 bufs x 3 rows x 2 sides
        const int col = (t & 1) * 513;
        const int q = t >> 1;          // 0..11
        const int r = q % 3;
        const int bu = (q / 3) & 1;
        if (q < 6) lsA[bu][r][col] = 0.0f;
        else       lsB[bu][r][col] = 0.0f;
    }

    v2f zz; zz.x = 0.0f; zz.y = 0.0f;

    // staging registers: 3 rows x {A,B}, own float2 each (12 VGPR)
    v2f sa0, sa1, sa2, sb0, sb1, sb2;

    // rolling window of horizontal conv sums: [2 cols][3 row slots]
    float h1[2][3], h2[2][3], h11[2][3], h22[2][3], h12[2][3];
    float tsum = 0.0f;

    // load 3 rows (SROW..SROW+2) own-float2; uniform guards (zeros off-image)
#define LOAD3(SROW) do {                                                      \
    const int g_ = (SROW);                                                    \
    sa0 = (g_ >= 0 && g_ < IMG_H) ? *(const v2f*)(A + (size_t)g_ * IMG_W + x) : zz;       \
    sb0 = (g_ >= 0 && g_ < IMG_H) ? *(const v2f*)(B + (size_t)g_ * IMG_W + x) : zz;       \
    sa1 = (g_ + 1 < IMG_H) ? *(const v2f*)(A + (size_t)(g_ + 1) * IMG_W + x) : zz;        \
    sb1 = (g_ + 1 < IMG_H) ? *(const v2f*)(B + (size_t)(g_ + 1) * IMG_W + x) : zz;        \
    sa2 = (g_ + 2 < IMG_H) ? *(const v2f*)(A + (size_t)(g_ + 2) * IMG_W + x) : zz;        \
    sb2 = (g_ + 2 < IMG_H) ? *(const v2f*)(B + (size_t)(g_ + 2) * IMG_W + x) : zz;        \
} while (0)

    // write held 3 rows into buffer BU (compiler merges to ds_write2_b32)
#define WRITE3(BU) do {                                                       \
    lsA[BU][0][1 + x] = sa0.x; lsA[BU][0][2 + x] = sa0.y;                     \
    lsA[BU][1][1 + x] = sa1.x; lsA[BU][1][2 + x] = sa1.y;                     \
    lsA[BU][2][1 + x] = sa2.x; lsA[BU][2][2 + x] = sa2.y;                     \
    lsB[BU][0][1 + x] = sb0.x; lsB[BU][0][2 + x] = sb0.y;                     \
    lsB[BU][1][1 + x] = sb1.x; lsB[BU][1][2 + x] = sb1.y;                     \
    lsB[BU][2][1 + x] = sb2.x; lsB[BU][2][2 + x] = sb2.y;                     \
} while (0)

    // one row-step: read cols x-1..x+2 from LDS row R of buffer BU,
    // horizontal 3-tap into window slot S (exact r0/r2 arithmetic)
#define HROW(BU, R, S) do {                                                   \
    const v2f alo = *(const v2f*)&lsA[BU][R][x];                              \
    const v2f ahi = *(const v2f*)&lsA[BU][R][x + 2];                          \
    const v2f blo = *(const v2f*)&lsB[BU][R][x];                              \
    const v2f bhi = *(const v2f*)&lsB[BU][R][x + 2];                          \
    const float am = alo.x, a0 = alo.y, a1 = ahi.x, ap = ahi.y;               \
    const float bm = blo.x, b0 = blo.y, b1 = bhi.x, bp = bhi.y;               \
    const float qa0 = am * am, qa1 = a0 * a0, qa2 = a1 * a1, qa3 = ap * ap;   \
    const float qb0 = bm * bm, qb1 = b0 * b0, qb2 = b1 * b1, qb3 = bp * bp;   \
    const float p0 = am * bm, p1 = a0 * b0, p2 = a1 * b1, p3 = ap * bp;       \
    h1[0][S]  = W_E * (am + a1) + W_C * a0;                                   \
    h1[1][S]  = W_E * (a0 + ap) + W_C * a1;                                   \
    h2[0][S]  = W_E * (bm + b1) + W_C * b0;                                   \
    h2[1][S]  = W_E * (b0 + bp) + W_C * b1;                                   \
    h11[0][S] = W_E * (qa0 + qa2) + W_C * qa1;                                \
    h11[1][S] = W_E * (qa1 + qa3) + W_C * qa2;                                \
    h22[0][S] = W_E * (qb0 + qb2) + W_C * qb1;                                \
    h22[1][S] = W_E * (qb1 + qb3) + W_C * qb2;                                \
    h12[0][S] = W_E * (p0 + p2) + W_C * p1;                                   \
    h12[1][S] = W_E * (p1 + p3) + W_C * p2;                                   \
} while (0)

    // vertical 3-tap + SSIM; ends = slots E0,E1, middle = MID
#define VOUT(E0, E1, MID) do {                                                \
    _Pragma("unroll")                                                         \
    for (int c = 0; c < 2; ++c) {                                             \
        const float mu1 = W_E * (h1[c][E0] + h1[c][E1]) + W_C * h1[c][MID];   \
        const float mu2 = W_E * (h2[c][E0] + h2[c][E1]) + W_C * h2[c][MID];   \
        const float e11 = W_E * (h11[c][E0] + h11[c][E1]) + W_C * h11[c][MID];\
        const float e22 = W_E * (h22[c][E0] + h22[c][E1]) + W_C * h22[c][MID];\
        const float e12 = W_E * (h12[c][E0] + h12[c][E1]) + W_C * h12[c][MID];\
        const float mu1s = mu1 * mu1, mu2s = mu2 * mu2, m12 = mu1 * mu2;      \
        const float s11 = e11 - mu1s, s22 = e22 - mu2s, s12 = e12 - m12;      \
        const float num = (2.0f * m12 + C1c) * (2.0f * s12 + C2c);            \
        const float den = (mu1s + mu2s + C1c) * (s11 + s22 + C2c);            \
        tsum += num / den;                                                    \
    }                                                                         \
} while (0)

    // input row i (global y0-1+i), i = 3s + r; slot = i%3 = r for every s.
    // ---- prologue: stage0 (rows y0-1..y0+1) -> buf0; stage1 -> regs ----
    LOAD3(y0 - 1);
    WRITE3(0);
    LOAD3(y0 + 2);
    __syncthreads();

    // ---- s=0 (buf0): i=0,1,2; first output at i=2 ----
    WRITE3(1);                 // stage1 -> buf1
    LOAD3(y0 + 5);             // stage2 in flight during compute
    HROW(0, 0, 0);
    HROW(0, 1, 1);
    HROW(0, 2, 2); VOUT(2, 0, 1);
    __syncthreads();

    int srow = y0 + 8;         // next stage to load = stage3 rows y0+8..
    // ---- s=1..8: four (odd,even) pairs, loop kept rolled ----
#pragma unroll 1
    for (int p = 0; p < 4; ++p) {
        // s odd: consume buf1
        WRITE3(0); LOAD3(srow); srow += 3;
        HROW(1, 0, 0); VOUT(0, 1, 2);
        HROW(1, 1, 1); VOUT(1, 2, 0);
        HROW(1, 2, 2); VOUT(2, 0, 1);
        __syncthreads();
        // s even: consume buf0
        WRITE3(1); LOAD3(srow); srow += 3;
        HROW(0, 0, 0); VOUT(0, 1, 2);
        HROW(0, 1, 1); VOUT(1, 2, 0);
        HROW(0, 2, 2); VOUT(2, 0, 1);
        __syncthreads();
    }

    // ---- s=9 (buf1): loads stage11 (rows y0+32.., guarded zeros) ----
    WRITE3(0); LOAD3(srow);    // srow = y0+32
    HROW(1, 0, 0); VOUT(0, 1, 2);
    HROW(1, 1, 1); VOUT(1, 2, 0);
    HROW(1, 2, 2); VOUT(2, 0, 1);
    __syncthreads();

    // ---- s=10 (buf0): i=30,31,32 ----
    WRITE3(1);                 // stage11 -> buf1 (only row 0 consumed)
    HROW(0, 0, 0); VOUT(0, 1, 2);
    HROW(0, 1, 1); VOUT(1, 2, 0);
    HROW(0, 2, 2); VOUT(2, 0, 1);
    __syncthreads();

    // ---- s=11 (buf1): i=33 -> last output row y0+31 ----
    HROW(1, 0, 0); VOUT(0, 1, 2);

#undef LOAD3
#undef WRITE3
#undef HROW
#undef VOUT

    // 64-lane wave reduction (f32, same order as before)
#pragma unroll
    for (int o = 32; o >= 1; o >>= 1)
        tsum += __shfl_xor(tsum, o, 64);

    __shared__ float wpart[4];
    if ((t & 63) == 0) wpart[t >> 6] = tsum;
    __syncthreads();
    if (t == 0) {
        partial[(size_t)blockIdx.y * gridDim.x + blockIdx.x] =
            (double)wpart[0] + (double)wpart[1] +
            (double)wpart[2] + (double)wpart[3];
    }
}

// Reduce 1536 per-block double partials -> out = 1 - sum. One block.
__global__ __launch_bounds__(256) void ssim_fin_kernel(
    const double* __restrict__ partial, float* __restrict__ out, int n)
{
    const int t = threadIdx.x;
    double s = 0.0;
    for (int i = t; i < n; i += 256) s += partial[i];
#pragma unroll
    for (int o = 32; o >= 1; o >>= 1)
        s += __shfl_xor(s, o, 64);
    __shared__ double w[4];
    if ((t & 63) == 0) w[t >> 6] = s;
    __syncthreads();
    if (t == 0)
        out[0] = 1.0f - (float)(w[0] + w[1] + w[2] + w[3]);
}

extern "C" void kernel_launch(void* const* d_in, const int* in_sizes, int n_in,
                              void* d_out, int out_size, void* d_ws, size_t ws_size,
                              hipStream_t stream) {
    const float* img1 = (const float*)d_in[0];
    const float* img2 = (const float*)d_in[1];
    float* out = (float*)d_out;
    double* partial = (double*)d_ws;  // needs 16*96*8 = 12288 B of workspace

    const int planes = in_sizes[0] / (IMG_H * IMG_W);  // 32*3 = 96

    dim3 grid(NBX, planes);
    ssim_main_kernel<<<grid, 256, 0, stream>>>(img1, img2, partial);
    ssim_fin_kernel<<<1, 256, 0, stream>>>(partial, out, NBX * planes);
}